// Round 1
// baseline (853.839 us; speedup 1.0000x reference)
//
#include <hip/hip_runtime.h>

#define N_NODES 100000
#define N_EDGES 500000
#define D 256
#define CAP 32          // bucket capacity per (node, relation); λ=5 ⇒ P(deg>32)≈1e-15

typedef __bf16 bf16x8 __attribute__((ext_vector_type(8)));
typedef float  f32x4  __attribute__((ext_vector_type(4)));

// ---- bf16 helpers (manual, RNE) -------------------------------------------
__device__ __forceinline__ unsigned short f2bf(float f) {
    unsigned int u = __float_as_uint(f);
    u += 0x7fffu + ((u >> 16) & 1u);
    return (unsigned short)(u >> 16);
}
__device__ __forceinline__ float bf2f(unsigned short b) {
    return __uint_as_float(((unsigned int)b) << 16);
}
__device__ __forceinline__ float bfu_lo(unsigned u) { return __uint_as_float(u << 16); }
__device__ __forceinline__ float bfu_hi(unsigned u) { return __uint_as_float(u & 0xffff0000u); }

// ---------------------------------------------------------------------------
// Prep kernel, WAVE-granular role interleave (unchanged from round 8).
// Of every 22 waves: 16 convert, 5 bucket, 1 W-prep.
// ---------------------------------------------------------------------------
#define PREP_BLOCKS 17188   // ceil(22*3125 waves / 4 per block)

__global__ __launch_bounds__(256) void prep_kernel(
    const float* __restrict__ x, unsigned short* __restrict__ xb,
    const float* __restrict__ Ws, const float* __restrict__ W1,
    const float* __restrict__ W2, unsigned short* __restrict__ Wt,
    const int* __restrict__ src1, const int* __restrict__ dst1,
    const int* __restrict__ src2, const int* __restrict__ dst2,
    int* __restrict__ cnt1, int* __restrict__ cnt2,
    int* __restrict__ bkt1, int* __restrict__ bkt2)
{
    const int wid  = blockIdx.x * 4 + (threadIdx.x >> 6);  // global wave id
    const int lane = threadIdx.x & 63;
    const int group = wid / 22;
    const int pos   = wid - group * 22;

    if (pos < 16) {
        // ---- convert role: x fp32 -> xb bf16, 8 elems/lane, coalesced ----
        int cw = group * 16 + pos;
        if (cw >= 50000) return;
        size_t i = (size_t)cw * 512 + (size_t)lane * 8;
        float4 a = *(const float4*)(x + i);
        float4 c = *(const float4*)(x + i + 4);
        union { unsigned short s[8]; uint4 u; } o;
        o.s[0] = f2bf(a.x); o.s[1] = f2bf(a.y); o.s[2] = f2bf(a.z); o.s[3] = f2bf(a.w);
        o.s[4] = f2bf(c.x); o.s[5] = f2bf(c.y); o.s[6] = f2bf(c.z); o.s[7] = f2bf(c.w);
        *(uint4*)(xb + i) = o.u;
    } else if (pos < 21) {
        // ---- bucket role: 1 edge/lane, cnt/bkt atomics (L2-resident) ----
        int bw = group * 5 + (pos - 16);
        int e = bw * 64 + lane;
        if (e >= 2 * N_EDGES) return;
        bool r2 = (e >= N_EDGES);
        const int* src = r2 ? src2 : src1;
        const int* dst = r2 ? dst2 : dst1;
        int* cnt = r2 ? cnt2 : cnt1;
        int* bkt = r2 ? bkt2 : bkt1;
        int ei = r2 ? e - N_EDGES : e;
        int s = src[ei], d = dst[ei];
        int p = atomicAdd(&cnt[d], 1);
        if (p < CAP) bkt[d * CAP + p] = s;
    } else {
        // ---- W-prep role: Wt[n][k] = bf16(scale_k * W[k%256][n]) ----
        int idx = group * 64 + lane;
        if (idx >= 3 * D * D) return;
        int k = idx >> 8;
        int n = idx & (D - 1);
        const float* W = (k < D) ? Ws : (k < 2 * D ? W1 : W2);
        float scale = (k < D) ? 1.1f : 1.0f;
        Wt[(size_t)n * (3 * D) + k] = f2bf(W[(size_t)(k & (D - 1)) * D + n] * scale);
    }
}

// ---------------------------------------------------------------------------
// Fused gather + MFMA GEMM (round-9 change):
//   out = relu( [xb | gather1(xb) | gather2(xb)] @ Wt^T + bias )
// The former gather_kernel (full-row reduce -> xa1/xa2 in HBM -> re-read) is
// folded into A-staging: K-tiles 0-7 load xb rows contiguously; tiles 8-23
// COMPUTE the A-tile slice: per 4-thread node-group, sum <=CAP 64B chunks of
// xb (one cache line per edge per tile; same total L3 bytes as full-row
// gather, zero HBM round trip). Bucket ids staged once per block into LDS.
// Chunk loads issue in the prefetch slot (overlap current tile's MFMA);
// fp32 fold + bf16 pack happen post-MFMA, feeding next tile's ds_write.
// LDS swizzle (chunk c -> c ^ ((row>>1)&3)) retained: bank-conflict-free.
// ---------------------------------------------------------------------------
__global__ __launch_bounds__(512, 4) void gemm_kernel(
    const unsigned short* __restrict__ xb,
    const int* __restrict__ cnt1, const int* __restrict__ cnt2,
    const int* __restrict__ bkt1, const int* __restrict__ bkt2,
    const unsigned short* __restrict__ Wt,   // [256 n][768 k] bf16, pre-scaled
    const float* __restrict__ bias, float* __restrict__ out)
{
    __shared__ unsigned short Alds[128 * 32];   // [row][swizzled k-chunk] 8 KB
    __shared__ unsigned short Blds[256 * 32];   // [n][swizzled k-chunk] 16 KB
    __shared__ int idsL[2 * 128 * CAP];         // bucket ids, both rels, 32 KB

    const int tid  = threadIdx.x;
    const int lane = tid & 63;
    const int wave = tid >> 6;          // 0..7
    const int quad = lane >> 4;
    const int l15  = lane & 15;
    const int m0 = blockIdx.x * 128;
    const int wm = (wave >> 2) * 64;    // 2 m-tiles x 4 n-tiles of 64
    const int wn = (wave & 3) * 64;

    // Staging geometry: thread -> (row, 16B chunk kq). A: 512 slots (128x4).
    // B: 1024 slots (256x4), 2 per thread. Swizzled LDS offsets (shorts).
    const int rowA = tid >> 2, kqA = tid & 3;
    int mA = m0 + rowA; if (mA >= N_NODES) mA = N_NODES - 1;
    const int wAoff  = rowA * 32 + ((kqA ^ ((rowA >> 1) & 3)) * 8);
    const int nB0 = tid >> 2, nB1 = nB0 + 128;
    const int wB0off = nB0 * 32 + ((kqA ^ ((nB0 >> 1) & 3)) * 8);
    const int wB1off = nB1 * 32 + ((kqA ^ ((nB1 >> 1) & 3)) * 8);
    const int swz = (l15 >> 1) & 3;     // read-side chunk swizzle (row>>1)&3

    // ---- stage bucket ids into LDS: 8192 ints, 16 per thread (half a row) --
    {
        int rel = tid >> 8;                  // 0 | 1
        int n   = (tid & 255) >> 1;          // local node 0..127
        int h   = (tid & 1) << 4;            // half-row offset in ints
        int nc  = m0 + n; if (nc >= N_NODES) nc = N_NODES - 1;
        const int* bsrc = (rel ? bkt2 : bkt1) + (size_t)nc * CAP + h;
        int* ldst = idsL + rel * (128 * CAP) + n * CAP + h;
        uint4 b0 = *(const uint4*)(bsrc + 0);
        uint4 b1 = *(const uint4*)(bsrc + 4);
        uint4 b2 = *(const uint4*)(bsrc + 8);
        uint4 b3 = *(const uint4*)(bsrc + 12);
        *(uint4*)(ldst + 0)  = b0;
        *(uint4*)(ldst + 4)  = b1;
        *(uint4*)(ldst + 8)  = b2;
        *(uint4*)(ldst + 12) = b3;
    }

    // Per-thread gather state for this thread's node (4 threads share a node).
    int c1 = cnt1[mA]; if (c1 > CAP) c1 = CAP;
    int c2 = cnt2[mA]; if (c2 > CAP) c2 = CAP;
    const int* myids1 = idsL + rowA * CAP;
    const int* myids2 = idsL + (128 * CAP) + rowA * CAP;

    f32x4 acc[4][4] = {};

    // Prefetch kt=0 (self relation: contiguous xb row chunk) + B.
    uint4 ra  = *(const uint4*)(xb + (size_t)mA * D + kqA * 8);
    uint4 rb0 = *(const uint4*)(Wt + (size_t)nB0 * (3 * D) + kqA * 8);
    uint4 rb1 = *(const uint4*)(Wt + (size_t)nB1 * (3 * D) + kqA * 8);

    uint4 gv[8];

    for (int kt = 0; kt < 24; ++kt) {
        *(uint4*)(Alds + wAoff)  = ra;
        *(uint4*)(Blds + wB0off) = rb0;
        *(uint4*)(Blds + wB1off) = rb1;
        __syncthreads();   // also orders idsL staging before first gather use

        const int ktn = kt + 1;
        int cc = 0;
        const int* myids = myids1;
        if (ktn < 24) {
            if (ktn < 8) {
                // next tile still self relation: contiguous prefetch
                ra = *(const uint4*)(xb + (size_t)mA * D + ktn * 32 + kqA * 8);
            } else {
                // next tile is a gather tile: issue <=8 independent 16B
                // chunk loads now; they drain during this tile's MFMAs.
                const bool r2g = (ktn >= 16);
                cc    = r2g ? c2 : c1;
                myids = r2g ? myids2 : myids1;
                const int ks = (ktn - 8) & 7;
                const unsigned short* gbase = xb + ks * 32 + kqA * 8;
                #pragma unroll
                for (int e = 0; e < 8; ++e) {
                    if (e < cc) {
                        int s = myids[e];                    // LDS broadcast
                        gv[e] = *(const uint4*)(gbase + (size_t)s * D);
                    }
                }
            }
            rb0 = *(const uint4*)(Wt + (size_t)nB0 * (3 * D) + ktn * 32 + kqA * 8);
            rb1 = *(const uint4*)(Wt + (size_t)nB1 * (3 * D) + ktn * 32 + kqA * 8);
        }

        // ---- fragments + MFMA (B held across i to cap register liveness) --
        bf16x8 b0f = *(const bf16x8*)(Blds + (wn +  0 + l15) * 32 + ((quad ^ swz) * 8));
        bf16x8 b1f = *(const bf16x8*)(Blds + (wn + 16 + l15) * 32 + ((quad ^ swz) * 8));
        bf16x8 b2f = *(const bf16x8*)(Blds + (wn + 32 + l15) * 32 + ((quad ^ swz) * 8));
        bf16x8 b3f = *(const bf16x8*)(Blds + (wn + 48 + l15) * 32 + ((quad ^ swz) * 8));
        #pragma unroll
        for (int i = 0; i < 4; ++i) {
            bf16x8 afi = *(const bf16x8*)(Alds + (wm + i * 16 + l15) * 32 + ((quad ^ swz) * 8));
            acc[i][0] = __builtin_amdgcn_mfma_f32_16x16x32_bf16(afi, b0f, acc[i][0], 0, 0, 0);
            acc[i][1] = __builtin_amdgcn_mfma_f32_16x16x32_bf16(afi, b1f, acc[i][1], 0, 0, 0);
            acc[i][2] = __builtin_amdgcn_mfma_f32_16x16x32_bf16(afi, b2f, acc[i][2], 0, 0, 0);
            acc[i][3] = __builtin_amdgcn_mfma_f32_16x16x32_bf16(afi, b3f, acc[i][3], 0, 0, 0);
        }

        // ---- post-MFMA: fold gather chunks for tile ktn, pack bf16 -> ra --
        if (ktn >= 8 && ktn < 24) {
            const int ks = (ktn - 8) & 7;
            float s0 = 0.f, s1 = 0.f, s2 = 0.f, s3 = 0.f;
            float s4 = 0.f, s5 = 0.f, s6 = 0.f, s7 = 0.f;
            #pragma unroll
            for (int e = 0; e < 8; ++e) {
                if (e < cc) {
                    s0 += bfu_lo(gv[e].x); s1 += bfu_hi(gv[e].x);
                    s2 += bfu_lo(gv[e].y); s3 += bfu_hi(gv[e].y);
                    s4 += bfu_lo(gv[e].z); s5 += bfu_hi(gv[e].z);
                    s6 += bfu_lo(gv[e].w); s7 += bfu_hi(gv[e].w);
                }
            }
            if (cc > 8) {   // tail: P(deg>8)≈7% per node; ids are LDS-fast
                const unsigned short* gbase = xb + ks * 32 + kqA * 8;
                uint4 tv[8];
                #pragma unroll
                for (int e = 8; e < 16; ++e)
                    if (e < cc) tv[e - 8] = *(const uint4*)(gbase + (size_t)myids[e] * D);
                #pragma unroll
                for (int e = 8; e < 16; ++e)
                    if (e < cc) {
                        s0 += bfu_lo(tv[e-8].x); s1 += bfu_hi(tv[e-8].x);
                        s2 += bfu_lo(tv[e-8].y); s3 += bfu_hi(tv[e-8].y);
                        s4 += bfu_lo(tv[e-8].z); s5 += bfu_hi(tv[e-8].z);
                        s6 += bfu_lo(tv[e-8].w); s7 += bfu_hi(tv[e-8].w);
                    }
                for (int e = 16; e < cc; ++e) {   // ultra-rare (P≈2e-5)
                    uint4 t = *(const uint4*)(gbase + (size_t)myids[e] * D);
                    s0 += bfu_lo(t.x); s1 += bfu_hi(t.x);
                    s2 += bfu_lo(t.y); s3 += bfu_hi(t.y);
                    s4 += bfu_lo(t.z); s5 += bfu_hi(t.z);
                    s6 += bfu_lo(t.w); s7 += bfu_hi(t.w);
                }
            }
            ra.x = (unsigned)f2bf(s0) | ((unsigned)f2bf(s1) << 16);
            ra.y = (unsigned)f2bf(s2) | ((unsigned)f2bf(s3) << 16);
            ra.z = (unsigned)f2bf(s4) | ((unsigned)f2bf(s5) << 16);
            ra.w = (unsigned)f2bf(s6) | ((unsigned)f2bf(s7) << 16);
        }
        __syncthreads();
    }

    // Epilogue: D layout col=lane&15, row=quad*4+reg (m89/m91 verified).
    #pragma unroll
    for (int j = 0; j < 4; ++j) {
        int col = wn + j * 16 + l15;
        float bj = bias[col];
        #pragma unroll
        for (int i = 0; i < 4; ++i) {
            int rb = m0 + wm + i * 16 + quad * 4;
            #pragma unroll
            for (int r = 0; r < 4; ++r) {
                int m = rb + r;
                if (m < N_NODES)
                    __builtin_nontemporal_store(
                        fmaxf(acc[i][j][r] + bj, 0.f),
                        out + (size_t)m * D + col);
            }
        }
    }
}

extern "C" void kernel_launch(void* const* d_in, const int* in_sizes, int n_in,
                              void* d_out, int out_size, void* d_ws, size_t ws_size,
                              hipStream_t stream) {
    const float* x    = (const float*)d_in[0];
    const float* Ws   = (const float*)d_in[1];
    const float* W1   = (const float*)d_in[2];
    const float* W2   = (const float*)d_in[3];
    const float* bias = (const float*)d_in[4];
    const int* src1   = (const int*)d_in[5];
    const int* dst1   = (const int*)d_in[6];
    const int* src2   = (const int*)d_in[7];
    const int* dst2   = (const int*)d_in[8];
    float* out = (float*)d_out;

    // Workspace layout (xa1/xa2 eliminated by fusion; total 78.4 MB):
    char* p = (char*)d_ws;
    unsigned short* xb  = (unsigned short*)p; p += (size_t)N_NODES * D * 2;  // 51.2 MB
    int* cnt1 = (int*)p; p += (size_t)N_NODES * 4;                           // 0.4 MB
    int* cnt2 = (int*)p; p += (size_t)N_NODES * 4;                           // 0.4 MB
    int* bkt1 = (int*)p; p += (size_t)N_NODES * CAP * 4;                     // 12.8 MB
    int* bkt2 = (int*)p; p += (size_t)N_NODES * CAP * 4;                     // 12.8 MB
    unsigned short* Wt = (unsigned short*)p;                                 // 0.39 MB

    (void)hipMemsetAsync(cnt1, 0, (size_t)2 * N_NODES * 4, stream);

    prep_kernel<<<PREP_BLOCKS, 256, 0, stream>>>(
        x, xb, Ws, W1, W2, Wt, src1, dst1, src2, dst2, cnt1, cnt2, bkt1, bkt2);

    // Fused gather + MFMA GEMM + bias + relu, full-N blocks
    gemm_kernel<<<(N_NODES + 127) / 128, 512, 0, stream>>>(
        xb, cnt1, cnt2, bkt1, bkt2, Wt, bias, out);
}

// Round 2
// 663.944 us; speedup vs baseline: 1.2860x; 1.2860x over previous
//
#include <hip/hip_runtime.h>

#define N_NODES 100000
#define N_EDGES 500000
#define D 256
#define CAP 32          // bucket capacity per (node, relation); λ=5 ⇒ P(deg>32)≈1e-15
#define IDS_STRIDE 36   // idsL node stride in ints: 144B, 16B-aligned, bank=(4*row+e)%32

typedef __bf16 bf16x8 __attribute__((ext_vector_type(8)));
typedef float  f32x4  __attribute__((ext_vector_type(4)));

// ---- bf16 helpers (manual, RNE) -------------------------------------------
__device__ __forceinline__ unsigned short f2bf(float f) {
    unsigned int u = __float_as_uint(f);
    u += 0x7fffu + ((u >> 16) & 1u);
    return (unsigned short)(u >> 16);
}
__device__ __forceinline__ float bfu_lo(unsigned u) { return __uint_as_float(u << 16); }
__device__ __forceinline__ float bfu_hi(unsigned u) { return __uint_as_float(u & 0xffff0000u); }

// ---------------------------------------------------------------------------
// Prep kernel, WAVE-granular role interleave (unchanged).
// Of every 22 waves: 16 convert, 5 bucket, 1 W-prep.
// ---------------------------------------------------------------------------
#define PREP_BLOCKS 17188   // ceil(22*3125 waves / 4 per block)

__global__ __launch_bounds__(256) void prep_kernel(
    const float* __restrict__ x, unsigned short* __restrict__ xb,
    const float* __restrict__ Ws, const float* __restrict__ W1,
    const float* __restrict__ W2, unsigned short* __restrict__ Wt,
    const int* __restrict__ src1, const int* __restrict__ dst1,
    const int* __restrict__ src2, const int* __restrict__ dst2,
    int* __restrict__ cnt1, int* __restrict__ cnt2,
    int* __restrict__ bkt1, int* __restrict__ bkt2)
{
    const int wid  = blockIdx.x * 4 + (threadIdx.x >> 6);  // global wave id
    const int lane = threadIdx.x & 63;
    const int group = wid / 22;
    const int pos   = wid - group * 22;

    if (pos < 16) {
        // ---- convert role: x fp32 -> xb bf16, 8 elems/lane, coalesced ----
        int cw = group * 16 + pos;
        if (cw >= 50000) return;
        size_t i = (size_t)cw * 512 + (size_t)lane * 8;
        float4 a = *(const float4*)(x + i);
        float4 c = *(const float4*)(x + i + 4);
        union { unsigned short s[8]; uint4 u; } o;
        o.s[0] = f2bf(a.x); o.s[1] = f2bf(a.y); o.s[2] = f2bf(a.z); o.s[3] = f2bf(a.w);
        o.s[4] = f2bf(c.x); o.s[5] = f2bf(c.y); o.s[6] = f2bf(c.z); o.s[7] = f2bf(c.w);
        *(uint4*)(xb + i) = o.u;
    } else if (pos < 21) {
        // ---- bucket role: 1 edge/lane, cnt/bkt atomics (L2-resident) ----
        int bw = group * 5 + (pos - 16);
        int e = bw * 64 + lane;
        if (e >= 2 * N_EDGES) return;
        bool r2 = (e >= N_EDGES);
        const int* src = r2 ? src2 : src1;
        const int* dst = r2 ? dst2 : dst1;
        int* cnt = r2 ? cnt2 : cnt1;
        int* bkt = r2 ? bkt2 : bkt1;
        int ei = r2 ? e - N_EDGES : e;
        int s = src[ei], d = dst[ei];
        int p = atomicAdd(&cnt[d], 1);
        if (p < CAP) bkt[d * CAP + p] = s;
    } else {
        // ---- W-prep role: Wt[n][k] = bf16(scale_k * W[k%256][n]) ----
        int idx = group * 64 + lane;
        if (idx >= 3 * D * D) return;
        int k = idx >> 8;
        int n = idx & (D - 1);
        const float* W = (k < D) ? Ws : (k < 2 * D ? W1 : W2);
        float scale = (k < D) ? 1.1f : 1.0f;
        Wt[(size_t)n * (3 * D) + k] = f2bf(W[(size_t)(k & (D - 1)) * D + n] * scale);
    }
}

// ---------------------------------------------------------------------------
// Fused gather + MFMA GEMM, round-2 reschedule (fixes round-1 spill disaster):
//   out = relu( [xb | gather1(xb) | gather2(xb)] @ Wt^T + bias )
// Round-1 failure: gv[8]+tv[8]+Bfrags held live ACROSS the MFMA section under
// a 128-reg cap -> ~50 regs spilled to scratch (WRITE_SIZE 886MB), plus idsL
// stride 128B -> 16-way bank conflicts (6.9M).
// Fix:
//  * batch1 gather loads (<=8 pred 16B) issue BEFORE __syncthreads(); the
//    barrier's implicit vmcnt(0) drains them (TLP-hidden across 4 waves/SIMD).
//    Fold immediately after; batch2 (e=8..15) reuses gv with its own wait;
//    rare scalar tail >=16. NOTHING gather-related lives across MFMA.
//  * rb0/rb1 issue post-fold (in flight across MFMA, consumed next ds_write).
//  * idsL stride 36 ints: bank=(4*row+e)%32 -> 2-way (free per m136).
// Per-phase reg estimate: fold ~117, MFMA ~106 (+64-reg acc counted) -> fits
// the (512,4) 128-reg budget without spill.
// ---------------------------------------------------------------------------
__global__ __launch_bounds__(512, 4) void gemm_kernel(
    const unsigned short* __restrict__ xb,
    const int* __restrict__ cnt1, const int* __restrict__ cnt2,
    const int* __restrict__ bkt1, const int* __restrict__ bkt2,
    const unsigned short* __restrict__ Wt,   // [256 n][768 k] bf16, pre-scaled
    const float* __restrict__ bias, float* __restrict__ out)
{
    __shared__ unsigned short Alds[128 * 32];    // [row][swizzled k-chunk] 8 KB
    __shared__ unsigned short Blds[256 * 32];    // [n][swizzled k-chunk] 16 KB
    __shared__ int idsL[2 * 128 * IDS_STRIDE];   // bucket ids, padded, 36 KB

    const int tid  = threadIdx.x;
    const int lane = tid & 63;
    const int wave = tid >> 6;          // 0..7
    const int quad = lane >> 4;
    const int l15  = lane & 15;
    const int m0 = blockIdx.x * 128;
    const int wm = (wave >> 2) * 64;    // 2 m-tiles x 4 n-tiles of 64
    const int wn = (wave & 3) * 64;

    // Staging geometry: thread -> (row, 16B chunk kq). A: 512 slots (128x4).
    // B: 1024 slots (256x4), 2 per thread. Swizzled LDS offsets (shorts).
    const int rowA = tid >> 2, kqA = tid & 3;
    int mA = m0 + rowA; if (mA >= N_NODES) mA = N_NODES - 1;
    const int wAoff  = rowA * 32 + ((kqA ^ ((rowA >> 1) & 3)) * 8);
    const int nB0 = tid >> 2, nB1 = nB0 + 128;
    const int wB0off = nB0 * 32 + ((kqA ^ ((nB0 >> 1) & 3)) * 8);
    const int wB1off = nB1 * 32 + ((kqA ^ ((nB1 >> 1) & 3)) * 8);
    const int swz = (l15 >> 1) & 3;     // read-side chunk swizzle (row>>1)&3

    // ---- stage bucket ids into LDS: 16 ints per thread (half a node row) --
    {
        int rel = tid >> 8;                  // 0 | 1
        int n   = (tid & 255) >> 1;          // local node 0..127
        int h   = (tid & 1) << 4;            // half-row offset in ints
        int nc  = m0 + n; if (nc >= N_NODES) nc = N_NODES - 1;
        const int* bsrc = (rel ? bkt2 : bkt1) + (size_t)nc * CAP + h;
        int* ldst = idsL + (rel * 128 + n) * IDS_STRIDE + h;
        uint4 b0 = *(const uint4*)(bsrc + 0);
        uint4 b1 = *(const uint4*)(bsrc + 4);
        uint4 b2 = *(const uint4*)(bsrc + 8);
        uint4 b3 = *(const uint4*)(bsrc + 12);
        *(uint4*)(ldst + 0)  = b0;
        *(uint4*)(ldst + 4)  = b1;
        *(uint4*)(ldst + 8)  = b2;
        *(uint4*)(ldst + 12) = b3;
    }

    // Per-thread gather counts (4 threads share a node).
    int c1 = cnt1[mA]; if (c1 > CAP) c1 = CAP;
    int c2 = cnt2[mA]; if (c2 > CAP) c2 = CAP;

    f32x4 acc[4][4] = {};

    // Prologue prefetch kt=0 (self relation) + B.
    uint4 ra  = *(const uint4*)(xb + (size_t)mA * D + kqA * 8);
    uint4 rb0 = *(const uint4*)(Wt + (size_t)nB0 * (3 * D) + kqA * 8);
    uint4 rb1 = *(const uint4*)(Wt + (size_t)nB1 * (3 * D) + kqA * 8);

    #define FOLD(v) { s0 += bfu_lo((v).x); s1 += bfu_hi((v).x); \
                      s2 += bfu_lo((v).y); s3 += bfu_hi((v).y); \
                      s4 += bfu_lo((v).z); s5 += bfu_hi((v).z); \
                      s6 += bfu_lo((v).w); s7 += bfu_hi((v).w); }

    for (int kt = 0; kt < 24; ++kt) {
        // ---- stage tile kt into LDS ----
        *(uint4*)(Alds + wAoff)  = ra;
        *(uint4*)(Blds + wB0off) = rb0;
        *(uint4*)(Blds + wB1off) = rb1;

        // ---- pre-barrier: issue next tile's A source loads ----
        const int ktn = kt + 1;
        uint4 gv[8];
        int cc = 0;
        const int* myids = idsL;                    // overwritten below when used
        const unsigned short* gbase = xb;
        if (ktn < 24) {
            if (ktn < 8) {
                // self relation: contiguous row chunk
                ra = *(const uint4*)(xb + (size_t)mA * D + ktn * 32 + kqA * 8);
            } else {
                const bool r2g = (ktn >= 16);
                cc    = r2g ? c2 : c1;
                myids = idsL + ((r2g ? 128 : 0) + rowA) * IDS_STRIDE;
                const int ks = (ktn - 8) & 7;
                gbase = xb + ks * 32 + kqA * 8;
                #pragma unroll
                for (int e = 0; e < 8; ++e)
                    if (e < cc) gv[e] = *(const uint4*)(gbase + (size_t)myids[e] * D);
            }
        }
        __syncthreads();   // drains batch1 + orders LDS staging

        // ---- post-barrier: fold gather into bf16 ra (gather tiles only) ---
        if (ktn >= 8 && ktn < 24) {
            float s0 = 0.f, s1 = 0.f, s2 = 0.f, s3 = 0.f;
            float s4 = 0.f, s5 = 0.f, s6 = 0.f, s7 = 0.f;
            #pragma unroll
            for (int e = 0; e < 8; ++e)
                if (e < cc) FOLD(gv[e]);
            // batch2: e=8..15, reuse gv (P(deg>8)≈7% per node)
            #pragma unroll
            for (int e = 8; e < 16; ++e)
                if (e < cc) gv[e - 8] = *(const uint4*)(gbase + (size_t)myids[e] * D);
            #pragma unroll
            for (int e = 8; e < 16; ++e)
                if (e < cc) FOLD(gv[e - 8]);
            if (cc > 16) {   // ultra-rare (P(deg>16)≈3e-6 per node)
                for (int e = 16; e < cc; ++e) {
                    uint4 t = *(const uint4*)(gbase + (size_t)myids[e] * D);
                    FOLD(t);
                }
            }
            ra.x = (unsigned)f2bf(s0) | ((unsigned)f2bf(s1) << 16);
            ra.y = (unsigned)f2bf(s2) | ((unsigned)f2bf(s3) << 16);
            ra.z = (unsigned)f2bf(s4) | ((unsigned)f2bf(s5) << 16);
            ra.w = (unsigned)f2bf(s6) | ((unsigned)f2bf(s7) << 16);
        }

        // ---- issue next B panel (in flight across MFMA) ----
        if (ktn < 24) {
            rb0 = *(const uint4*)(Wt + (size_t)nB0 * (3 * D) + ktn * 32 + kqA * 8);
            rb1 = *(const uint4*)(Wt + (size_t)nB1 * (3 * D) + ktn * 32 + kqA * 8);
        }

        // ---- fragments + MFMA (B held across i; A streamed) ----
        bf16x8 b0f = *(const bf16x8*)(Blds + (wn +  0 + l15) * 32 + ((quad ^ swz) * 8));
        bf16x8 b1f = *(const bf16x8*)(Blds + (wn + 16 + l15) * 32 + ((quad ^ swz) * 8));
        bf16x8 b2f = *(const bf16x8*)(Blds + (wn + 32 + l15) * 32 + ((quad ^ swz) * 8));
        bf16x8 b3f = *(const bf16x8*)(Blds + (wn + 48 + l15) * 32 + ((quad ^ swz) * 8));
        #pragma unroll
        for (int i = 0; i < 4; ++i) {
            bf16x8 afi = *(const bf16x8*)(Alds + (wm + i * 16 + l15) * 32 + ((quad ^ swz) * 8));
            acc[i][0] = __builtin_amdgcn_mfma_f32_16x16x32_bf16(afi, b0f, acc[i][0], 0, 0, 0);
            acc[i][1] = __builtin_amdgcn_mfma_f32_16x16x32_bf16(afi, b1f, acc[i][1], 0, 0, 0);
            acc[i][2] = __builtin_amdgcn_mfma_f32_16x16x32_bf16(afi, b2f, acc[i][2], 0, 0, 0);
            acc[i][3] = __builtin_amdgcn_mfma_f32_16x16x32_bf16(afi, b3f, acc[i][3], 0, 0, 0);
        }
        __syncthreads();
    }
    #undef FOLD

    // Epilogue: D layout col=lane&15, row=quad*4+reg (m89/m91 verified).
    #pragma unroll
    for (int j = 0; j < 4; ++j) {
        int col = wn + j * 16 + l15;
        float bj = bias[col];
        #pragma unroll
        for (int i = 0; i < 4; ++i) {
            int rb = m0 + wm + i * 16 + quad * 4;
            #pragma unroll
            for (int r = 0; r < 4; ++r) {
                int m = rb + r;
                if (m < N_NODES)
                    __builtin_nontemporal_store(
                        fmaxf(acc[i][j][r] + bj, 0.f),
                        out + (size_t)m * D + col);
            }
        }
    }
}

extern "C" void kernel_launch(void* const* d_in, const int* in_sizes, int n_in,
                              void* d_out, int out_size, void* d_ws, size_t ws_size,
                              hipStream_t stream) {
    const float* x    = (const float*)d_in[0];
    const float* Ws   = (const float*)d_in[1];
    const float* W1   = (const float*)d_in[2];
    const float* W2   = (const float*)d_in[3];
    const float* bias = (const float*)d_in[4];
    const int* src1   = (const int*)d_in[5];
    const int* dst1   = (const int*)d_in[6];
    const int* src2   = (const int*)d_in[7];
    const int* dst2   = (const int*)d_in[8];
    float* out = (float*)d_out;

    // Workspace layout (total 78.4 MB):
    char* p = (char*)d_ws;
    unsigned short* xb  = (unsigned short*)p; p += (size_t)N_NODES * D * 2;  // 51.2 MB
    int* cnt1 = (int*)p; p += (size_t)N_NODES * 4;                           // 0.4 MB
    int* cnt2 = (int*)p; p += (size_t)N_NODES * 4;                           // 0.4 MB
    int* bkt1 = (int*)p; p += (size_t)N_NODES * CAP * 4;                     // 12.8 MB
    int* bkt2 = (int*)p; p += (size_t)N_NODES * CAP * 4;                     // 12.8 MB
    unsigned short* Wt = (unsigned short*)p;                                 // 0.39 MB

    (void)hipMemsetAsync(cnt1, 0, (size_t)2 * N_NODES * 4, stream);

    prep_kernel<<<PREP_BLOCKS, 256, 0, stream>>>(
        x, xb, Ws, W1, W2, Wt, src1, dst1, src2, dst2, cnt1, cnt2, bkt1, bkt2);

    // Fused gather + MFMA GEMM + bias + relu, full-N blocks
    gemm_kernel<<<(N_NODES + 127) / 128, 512, 0, stream>>>(
        xb, cnt1, cnt2, bkt1, bkt2, Wt, bias, out);
}

// Round 3
// 455.190 us; speedup vs baseline: 1.8758x; 1.4586x over previous
//
#include <hip/hip_runtime.h>

#define N_NODES 100000
#define N_EDGES 500000
#define D 256
#define CAP 32          // bucket capacity per (node, relation); λ=5 ⇒ P(deg>32)≈1e-15
#define IDS_STRIDE 36   // idsL node stride in ints: 144B, 16B-aligned, bank=(4*row+e)%32

typedef __bf16 bf16x8 __attribute__((ext_vector_type(8)));
typedef float  f32x4  __attribute__((ext_vector_type(4)));

// ---- bf16 helpers (manual, RNE) -------------------------------------------
__device__ __forceinline__ unsigned short f2bf(float f) {
    unsigned int u = __float_as_uint(f);
    u += 0x7fffu + ((u >> 16) & 1u);
    return (unsigned short)(u >> 16);
}
__device__ __forceinline__ float bfu_lo(unsigned u) { return __uint_as_float(u << 16); }
__device__ __forceinline__ float bfu_hi(unsigned u) { return __uint_as_float(u & 0xffff0000u); }

// ---------------------------------------------------------------------------
// Prep kernel, WAVE-granular role interleave (unchanged).
// Of every 22 waves: 16 convert, 5 bucket, 1 W-prep.
// ---------------------------------------------------------------------------
#define PREP_BLOCKS 17188   // ceil(22*3125 waves / 4 per block)

__global__ __launch_bounds__(256) void prep_kernel(
    const float* __restrict__ x, unsigned short* __restrict__ xb,
    const float* __restrict__ Ws, const float* __restrict__ W1,
    const float* __restrict__ W2, unsigned short* __restrict__ Wt,
    const int* __restrict__ src1, const int* __restrict__ dst1,
    const int* __restrict__ src2, const int* __restrict__ dst2,
    int* __restrict__ cnt1, int* __restrict__ cnt2,
    int* __restrict__ bkt1, int* __restrict__ bkt2)
{
    const int wid  = blockIdx.x * 4 + (threadIdx.x >> 6);  // global wave id
    const int lane = threadIdx.x & 63;
    const int group = wid / 22;
    const int pos   = wid - group * 22;

    if (pos < 16) {
        // ---- convert role: x fp32 -> xb bf16, 8 elems/lane, coalesced ----
        int cw = group * 16 + pos;
        if (cw >= 50000) return;
        size_t i = (size_t)cw * 512 + (size_t)lane * 8;
        float4 a = *(const float4*)(x + i);
        float4 c = *(const float4*)(x + i + 4);
        union { unsigned short s[8]; uint4 u; } o;
        o.s[0] = f2bf(a.x); o.s[1] = f2bf(a.y); o.s[2] = f2bf(a.z); o.s[3] = f2bf(a.w);
        o.s[4] = f2bf(c.x); o.s[5] = f2bf(c.y); o.s[6] = f2bf(c.z); o.s[7] = f2bf(c.w);
        *(uint4*)(xb + i) = o.u;
    } else if (pos < 21) {
        // ---- bucket role: 1 edge/lane, cnt/bkt atomics (L2-resident) ----
        int bw = group * 5 + (pos - 16);
        int e = bw * 64 + lane;
        if (e >= 2 * N_EDGES) return;
        bool r2 = (e >= N_EDGES);
        const int* src = r2 ? src2 : src1;
        const int* dst = r2 ? dst2 : dst1;
        int* cnt = r2 ? cnt2 : cnt1;
        int* bkt = r2 ? bkt2 : bkt1;
        int ei = r2 ? e - N_EDGES : e;
        int s = src[ei], d = dst[ei];
        int p = atomicAdd(&cnt[d], 1);
        if (p < CAP) bkt[d * CAP + p] = s;
    } else {
        // ---- W-prep role: Wt[n][k] = bf16(scale_k * W[k%256][n]) ----
        int idx = group * 64 + lane;
        if (idx >= 3 * D * D) return;
        int k = idx >> 8;
        int n = idx & (D - 1);
        const float* W = (k < D) ? Ws : (k < 2 * D ? W1 : W2);
        float scale = (k < D) ? 1.1f : 1.0f;
        Wt[(size_t)n * (3 * D) + k] = f2bf(W[(size_t)(k & (D - 1)) * D + n] * scale);
    }
}

// ---------------------------------------------------------------------------
// Fused gather + MFMA GEMM, round-3: KILL THE SPILL.
//   out = relu( [xb | gather1(xb) | gather2(xb)] @ Wt^T + bias )
// Round-2 post-mortem: VGPR_Count=64 — the (512,4) launch bound caps the
// unified file at 128 regs/wave; acc[4][4] takes 64 AGPRs, leaving 64 arch
// VGPRs for a ~90-reg working set -> ~25 regs spilled per gather tile ->
// 1.2 GB/dispatch scratch traffic (WRITE 754MB / FETCH 872MB), ~330 us.
// Fix: __launch_bounds__(512, 2) -> 256-reg budget, 1 block/CU. Demand
// (~155 unified) fits with headroom; occupancy 8 waves/CU is tolerable
// because all gather/B loads issue pre-barrier and the barrier's implicit
// vmcnt(0) drain doubles as the prefetch wait (exposed cost ~600cyc x 24
// tiles x 3 block-rounds ~ 18 us).
// Schedule per tile: ds_write staged regs -> issue kt+1 loads (gather gv[8]
// predicated | self ra; B rb0/rb1) -> barrier (loads arrive) -> frag
// ds_reads + 16 MFMA -> fold gv into bf16 ra (feeds next ds_write) ->
// barrier. Nothing waits on memory inside the compute phase.
// ---------------------------------------------------------------------------
__global__ __launch_bounds__(512, 2) void gemm_kernel(
    const unsigned short* __restrict__ xb,
    const int* __restrict__ cnt1, const int* __restrict__ cnt2,
    const int* __restrict__ bkt1, const int* __restrict__ bkt2,
    const unsigned short* __restrict__ Wt,   // [256 n][768 k] bf16, pre-scaled
    const float* __restrict__ bias, float* __restrict__ out)
{
    __shared__ unsigned short Alds[128 * 32];    // [row][swizzled k-chunk] 8 KB
    __shared__ unsigned short Blds[256 * 32];    // [n][swizzled k-chunk] 16 KB
    __shared__ int idsL[2 * 128 * IDS_STRIDE];   // bucket ids, padded, 36 KB

    const int tid  = threadIdx.x;
    const int lane = tid & 63;
    const int wave = tid >> 6;          // 0..7
    const int quad = lane >> 4;
    const int l15  = lane & 15;
    const int m0 = blockIdx.x * 128;
    const int wm = (wave >> 2) * 64;    // 2 m-tiles x 4 n-tiles of 64
    const int wn = (wave & 3) * 64;

    // Staging geometry: thread -> (row, 16B chunk kq). A: 512 slots (128x4).
    // B: 1024 slots (256x4), 2 per thread. Swizzled LDS offsets (shorts).
    const int rowA = tid >> 2, kqA = tid & 3;
    int mA = m0 + rowA; if (mA >= N_NODES) mA = N_NODES - 1;
    const int wAoff  = rowA * 32 + ((kqA ^ ((rowA >> 1) & 3)) * 8);
    const int nB0 = tid >> 2, nB1 = nB0 + 128;
    const int wB0off = nB0 * 32 + ((kqA ^ ((nB0 >> 1) & 3)) * 8);
    const int wB1off = nB1 * 32 + ((kqA ^ ((nB1 >> 1) & 3)) * 8);
    const int swz = (l15 >> 1) & 3;     // read-side chunk swizzle (row>>1)&3

    // ---- stage bucket ids into LDS: 16 ints per thread (half a node row) --
    {
        int rel = tid >> 8;                  // 0 | 1
        int n   = (tid & 255) >> 1;          // local node 0..127
        int h   = (tid & 1) << 4;            // half-row offset in ints
        int nc  = m0 + n; if (nc >= N_NODES) nc = N_NODES - 1;
        const int* bsrc = (rel ? bkt2 : bkt1) + (size_t)nc * CAP + h;
        int* ldst = idsL + (rel * 128 + n) * IDS_STRIDE + h;
        uint4 b0 = *(const uint4*)(bsrc + 0);
        uint4 b1 = *(const uint4*)(bsrc + 4);
        uint4 b2 = *(const uint4*)(bsrc + 8);
        uint4 b3 = *(const uint4*)(bsrc + 12);
        *(uint4*)(ldst + 0)  = b0;
        *(uint4*)(ldst + 4)  = b1;
        *(uint4*)(ldst + 8)  = b2;
        *(uint4*)(ldst + 12) = b3;
    }

    // Per-thread gather counts (4 threads share a node).
    int c1 = cnt1[mA]; if (c1 > CAP) c1 = CAP;
    int c2 = cnt2[mA]; if (c2 > CAP) c2 = CAP;

    f32x4 acc[4][4] = {};

    // Prologue prefetch kt=0 (self relation) + B.
    uint4 ra  = *(const uint4*)(xb + (size_t)mA * D + kqA * 8);
    uint4 rb0 = *(const uint4*)(Wt + (size_t)nB0 * (3 * D) + kqA * 8);
    uint4 rb1 = *(const uint4*)(Wt + (size_t)nB1 * (3 * D) + kqA * 8);

    #define FOLD(v) { s0 += bfu_lo((v).x); s1 += bfu_hi((v).x); \
                      s2 += bfu_lo((v).y); s3 += bfu_hi((v).y); \
                      s4 += bfu_lo((v).z); s5 += bfu_hi((v).z); \
                      s6 += bfu_lo((v).w); s7 += bfu_hi((v).w); }

    for (int kt = 0; kt < 24; ++kt) {
        // ---- stage tile kt into LDS ----
        *(uint4*)(Alds + wAoff)  = ra;
        *(uint4*)(Blds + wB0off) = rb0;
        *(uint4*)(Blds + wB1off) = rb1;

        // ---- pre-barrier: issue ALL of tile kt+1's source loads ----
        const int ktn = kt + 1;
        uint4 gv[8];
        int cc = 0;
        const int* myids = idsL;
        const unsigned short* gbase = xb;
        if (ktn < 24) {
            if (ktn < 8) {
                // self relation: contiguous row chunk
                ra = *(const uint4*)(xb + (size_t)mA * D + ktn * 32 + kqA * 8);
            } else {
                const bool r2g = (ktn >= 16);
                cc    = r2g ? c2 : c1;
                myids = idsL + ((r2g ? 128 : 0) + rowA) * IDS_STRIDE;
                const int ks = (ktn - 8) & 7;
                gbase = xb + ks * 32 + kqA * 8;
                #pragma unroll
                for (int e = 0; e < 8; ++e)
                    if (e < cc) gv[e] = *(const uint4*)(gbase + (size_t)myids[e] * D);
            }
            rb0 = *(const uint4*)(Wt + (size_t)nB0 * (3 * D) + ktn * 32 + kqA * 8);
            rb1 = *(const uint4*)(Wt + (size_t)nB1 * (3 * D) + ktn * 32 + kqA * 8);
        }
        __syncthreads();   // orders LDS staging; implicit vmcnt(0) = prefetch wait

        // ---- fragments + MFMA (tile kt) — no memory waits inside ----
        bf16x8 b0f = *(const bf16x8*)(Blds + (wn +  0 + l15) * 32 + ((quad ^ swz) * 8));
        bf16x8 b1f = *(const bf16x8*)(Blds + (wn + 16 + l15) * 32 + ((quad ^ swz) * 8));
        bf16x8 b2f = *(const bf16x8*)(Blds + (wn + 32 + l15) * 32 + ((quad ^ swz) * 8));
        bf16x8 b3f = *(const bf16x8*)(Blds + (wn + 48 + l15) * 32 + ((quad ^ swz) * 8));
        #pragma unroll
        for (int i = 0; i < 4; ++i) {
            bf16x8 afi = *(const bf16x8*)(Alds + (wm + i * 16 + l15) * 32 + ((quad ^ swz) * 8));
            acc[i][0] = __builtin_amdgcn_mfma_f32_16x16x32_bf16(afi, b0f, acc[i][0], 0, 0, 0);
            acc[i][1] = __builtin_amdgcn_mfma_f32_16x16x32_bf16(afi, b1f, acc[i][1], 0, 0, 0);
            acc[i][2] = __builtin_amdgcn_mfma_f32_16x16x32_bf16(afi, b2f, acc[i][2], 0, 0, 0);
            acc[i][3] = __builtin_amdgcn_mfma_f32_16x16x32_bf16(afi, b3f, acc[i][3], 0, 0, 0);
        }

        // ---- post-MFMA: fold gather chunks into bf16 ra (next ds_write) ---
        if (ktn >= 8 && ktn < 24) {
            float s0 = 0.f, s1 = 0.f, s2 = 0.f, s3 = 0.f;
            float s4 = 0.f, s5 = 0.f, s6 = 0.f, s7 = 0.f;
            #pragma unroll
            for (int e = 0; e < 8; ++e)
                if (e < cc) FOLD(gv[e]);
            if (cc > 8) {   // tail: P(deg>8)≈7% per node; reuse gv regs
                #pragma unroll
                for (int e = 8; e < 16; ++e)
                    if (e < cc) gv[e - 8] = *(const uint4*)(gbase + (size_t)myids[e] * D);
                #pragma unroll
                for (int e = 8; e < 16; ++e)
                    if (e < cc) FOLD(gv[e - 8]);
                for (int e = 16; e < cc; ++e) {   // ultra-rare (P≈3e-6)
                    uint4 t = *(const uint4*)(gbase + (size_t)myids[e] * D);
                    FOLD(t);
                }
            }
            ra.x = (unsigned)f2bf(s0) | ((unsigned)f2bf(s1) << 16);
            ra.y = (unsigned)f2bf(s2) | ((unsigned)f2bf(s3) << 16);
            ra.z = (unsigned)f2bf(s4) | ((unsigned)f2bf(s5) << 16);
            ra.w = (unsigned)f2bf(s6) | ((unsigned)f2bf(s7) << 16);
        }
        __syncthreads();
    }
    #undef FOLD

    // Epilogue: D layout col=lane&15, row=quad*4+reg (m89/m91 verified).
    #pragma unroll
    for (int j = 0; j < 4; ++j) {
        int col = wn + j * 16 + l15;
        float bj = bias[col];
        #pragma unroll
        for (int i = 0; i < 4; ++i) {
            int rb = m0 + wm + i * 16 + quad * 4;
            #pragma unroll
            for (int r = 0; r < 4; ++r) {
                int m = rb + r;
                if (m < N_NODES)
                    __builtin_nontemporal_store(
                        fmaxf(acc[i][j][r] + bj, 0.f),
                        out + (size_t)m * D + col);
            }
        }
    }
}

extern "C" void kernel_launch(void* const* d_in, const int* in_sizes, int n_in,
                              void* d_out, int out_size, void* d_ws, size_t ws_size,
                              hipStream_t stream) {
    const float* x    = (const float*)d_in[0];
    const float* Ws   = (const float*)d_in[1];
    const float* W1   = (const float*)d_in[2];
    const float* W2   = (const float*)d_in[3];
    const float* bias = (const float*)d_in[4];
    const int* src1   = (const int*)d_in[5];
    const int* dst1   = (const int*)d_in[6];
    const int* src2   = (const int*)d_in[7];
    const int* dst2   = (const int*)d_in[8];
    float* out = (float*)d_out;

    // Workspace layout (total 78.4 MB):
    char* p = (char*)d_ws;
    unsigned short* xb  = (unsigned short*)p; p += (size_t)N_NODES * D * 2;  // 51.2 MB
    int* cnt1 = (int*)p; p += (size_t)N_NODES * 4;                           // 0.4 MB
    int* cnt2 = (int*)p; p += (size_t)N_NODES * 4;                           // 0.4 MB
    int* bkt1 = (int*)p; p += (size_t)N_NODES * CAP * 4;                     // 12.8 MB
    int* bkt2 = (int*)p; p += (size_t)N_NODES * CAP * 4;                     // 12.8 MB
    unsigned short* Wt = (unsigned short*)p;                                 // 0.39 MB

    (void)hipMemsetAsync(cnt1, 0, (size_t)2 * N_NODES * 4, stream);

    prep_kernel<<<PREP_BLOCKS, 256, 0, stream>>>(
        x, xb, Ws, W1, W2, Wt, src1, dst1, src2, dst2, cnt1, cnt2, bkt1, bkt2);

    // Fused gather + MFMA GEMM + bias + relu, full-N blocks
    gemm_kernel<<<(N_NODES + 127) / 128, 512, 0, stream>>>(
        xb, cnt1, cnt2, bkt1, bkt2, Wt, bias, out);
}

// Round 4
// 418.545 us; speedup vs baseline: 2.0400x; 1.0876x over previous
//
#include <hip/hip_runtime.h>

#define N_NODES 100000
#define N_EDGES 500000
#define D 256
#define CAP 32          // bucket capacity per (node, relation); λ=5 ⇒ P(deg>32)≈1e-15
#define IDS_STRIDE 36   // idsL node stride in ints: 144B, 16B-aligned, bank=(4*row+e)%32

typedef __bf16 bf16x8 __attribute__((ext_vector_type(8)));
typedef float  f32x4  __attribute__((ext_vector_type(4)));

// ---- bf16 helpers (manual, RNE) -------------------------------------------
__device__ __forceinline__ unsigned short f2bf(float f) {
    unsigned int u = __float_as_uint(f);
    u += 0x7fffu + ((u >> 16) & 1u);
    return (unsigned short)(u >> 16);
}
__device__ __forceinline__ float bfu_lo(unsigned u) { return __uint_as_float(u << 16); }
__device__ __forceinline__ float bfu_hi(unsigned u) { return __uint_as_float(u & 0xffff0000u); }

// ---- async global->LDS, 16B per lane (dest = uniform base + lane*16) ------
__device__ __forceinline__ void glds16(const unsigned short* g, unsigned short* l) {
    __builtin_amdgcn_global_load_lds(
        (const __attribute__((address_space(1))) unsigned int*)g,
        (__attribute__((address_space(3))) unsigned int*)l,
        16, 0, 0);
}

// ---------------------------------------------------------------------------
// Prep kernel, WAVE-granular role interleave.
// Round-4 change: W-role writes Wt PRE-SWIZZLED (k' = k ^ (((n>>1)&3)<<3)) so
// the GEMM can stage B with linear-dest global_load_lds and still get the
// bank-conflict-free swizzled Blds layout (m173: swizzle source, LDS linear).
// ---------------------------------------------------------------------------
#define PREP_BLOCKS 17188   // ceil(22*3125 waves / 4 per block)

__global__ __launch_bounds__(256) void prep_kernel(
    const float* __restrict__ x, unsigned short* __restrict__ xb,
    const float* __restrict__ Ws, const float* __restrict__ W1,
    const float* __restrict__ W2, unsigned short* __restrict__ Wt,
    const int* __restrict__ src1, const int* __restrict__ dst1,
    const int* __restrict__ src2, const int* __restrict__ dst2,
    int* __restrict__ cnt1, int* __restrict__ cnt2,
    int* __restrict__ bkt1, int* __restrict__ bkt2)
{
    const int wid  = blockIdx.x * 4 + (threadIdx.x >> 6);  // global wave id
    const int lane = threadIdx.x & 63;
    const int group = wid / 22;
    const int pos   = wid - group * 22;

    if (pos < 16) {
        // ---- convert role: x fp32 -> xb bf16, 8 elems/lane, coalesced ----
        int cw = group * 16 + pos;
        if (cw >= 50000) return;
        size_t i = (size_t)cw * 512 + (size_t)lane * 8;
        float4 a = *(const float4*)(x + i);
        float4 c = *(const float4*)(x + i + 4);
        union { unsigned short s[8]; uint4 u; } o;
        o.s[0] = f2bf(a.x); o.s[1] = f2bf(a.y); o.s[2] = f2bf(a.z); o.s[3] = f2bf(a.w);
        o.s[4] = f2bf(c.x); o.s[5] = f2bf(c.y); o.s[6] = f2bf(c.z); o.s[7] = f2bf(c.w);
        *(uint4*)(xb + i) = o.u;
    } else if (pos < 21) {
        // ---- bucket role: 1 edge/lane, cnt/bkt atomics (L2-resident) ----
        int bw = group * 5 + (pos - 16);
        int e = bw * 64 + lane;
        if (e >= 2 * N_EDGES) return;
        bool r2 = (e >= N_EDGES);
        const int* src = r2 ? src2 : src1;
        const int* dst = r2 ? dst2 : dst1;
        int* cnt = r2 ? cnt2 : cnt1;
        int* bkt = r2 ? bkt2 : bkt1;
        int ei = r2 ? e - N_EDGES : e;
        int s = src[ei], d = dst[ei];
        int p = atomicAdd(&cnt[d], 1);
        if (p < CAP) bkt[d * CAP + p] = s;
    } else {
        // ---- W-prep role: Wt[n][k^swz] = bf16(scale_k * W[k%256][n]) ----
        int idx = group * 64 + lane;
        if (idx >= 3 * D * D) return;
        int k = idx >> 8;
        int n = idx & (D - 1);
        const float* W = (k < D) ? Ws : (k < 2 * D ? W1 : W2);
        float scale = (k < D) ? 1.1f : 1.0f;
        int dk = k ^ ((((n >> 1) & 3)) << 3);   // pre-swizzle 16B chunk slot
        Wt[(size_t)n * (3 * D) + dk] = f2bf(W[(size_t)(k & (D - 1)) * D + n] * scale);
    }
}

// ---------------------------------------------------------------------------
// Fused gather + MFMA GEMM, round-4: OCCUPANCY via register deletion.
//   out = relu( [xb | gather1(xb) | gather2(xb)] @ Wt^T + bias )
// Round-3 post-mortem: spill dead (WRITE=103MB) but 1 block/CU (unified 148
// regs) -> all 8 waves stall in lockstep at every barrier's implicit vmcnt(0)
// for ~600-900cy random-L3 gather latency; MfmaUtil 6%, 75% idle.
// Fix: shrink the register working set so 2 blocks/CU fit under (512,4):
//  * B staging via global_load_lds (zero regs); swizzle preserved by
//    PRE-SWIZZLED Wt (see prep). 2 glds/wave/tile.
//  * A self-tiles (kt<8) via global_load_lds with chunk-XOR applied to the
//    per-lane SOURCE address (LDS dest linear = swizzled content).
//  * gather in two 4-chunk batches: batch0 pre-barrier (arrives at barrier,
//    folded right after), batch1 issued pre-MFMA (latency hides under MFMA),
//    folded post-MFMA; rare tail (cc>8, ~7%) post-MFMA.
// Live across MFMA: gv[4](16) + sums(8) + frags(20) + addr(~12) ≈ 56 arch
// + 64 AGPR ≈ 120 unified ≤ 128 -> 2 blocks/CU, 16 waves: the other block's
// MFMA/fold phase hides this block's barrier stall (m114 overlap).
// ---------------------------------------------------------------------------
__global__ __launch_bounds__(512, 4) void gemm_kernel(
    const unsigned short* __restrict__ xb,
    const int* __restrict__ cnt1, const int* __restrict__ cnt2,
    const int* __restrict__ bkt1, const int* __restrict__ bkt2,
    const unsigned short* __restrict__ Wt,   // [256 n][768 k] bf16, PRE-SWIZZLED
    const float* __restrict__ bias, float* __restrict__ out)
{
    __shared__ unsigned short Alds[128 * 32];    // [row][swizzled k-chunk] 8 KB
    __shared__ unsigned short Blds[256 * 32];    // [n][swizzled k-chunk] 16 KB
    __shared__ int idsL[2 * 128 * IDS_STRIDE];   // bucket ids, padded, 36 KB

    const int tid  = threadIdx.x;
    const int lane = tid & 63;
    const int wave = tid >> 6;          // 0..7
    const int quad = lane >> 4;
    const int l15  = lane & 15;
    const int m0 = blockIdx.x * 128;
    const int wm = (wave >> 2) * 64;    // 2 m-tiles x 4 n-tiles of 64
    const int wn = (wave & 3) * 64;

    // Gather-staging geometry: thread -> (row, 16B chunk kq), 4 thr/node.
    const int rowA = tid >> 2, kqA = tid & 3;
    int mA = m0 + rowA; if (mA >= N_NODES) mA = N_NODES - 1;
    const int wAoff = rowA * 32 + ((kqA ^ ((rowA >> 1) & 3)) * 8);
    const int swz = (l15 >> 1) & 3;     // read-side chunk swizzle (row>>1)&3

    // glds source geometry (per wave slab of 16 rows; lane -> row,chunk)
    const int gr   = (lane >> 2);               // row within slab
    const int gch  = lane & 3;                  // dest chunk slot
    const int gswz = (lane >> 3) & 3;           // ((16i+gr)>>1)&3 == (gr>>1)&3
    int mSelf = m0 + (wave << 4) + gr; if (mSelf >= N_NODES) mSelf = N_NODES - 1;
    const unsigned short* aSelfSrc = xb + (size_t)mSelf * D + ((gch ^ gswz) << 3);
    const unsigned short* bSrc0 = Wt + (size_t)((wave << 4) + gr) * (3 * D) + (gch << 3);
    const unsigned short* bSrc1 = bSrc0 + (size_t)128 * (3 * D);
    unsigned short* aDst  = Alds + wave * 512;          // 1024B slab
    unsigned short* bDst0 = Blds + wave * 512;
    unsigned short* bDst1 = Blds + 4096 + wave * 512;

    // ---- stage bucket ids into LDS: 16 ints per thread (half a node row) --
    {
        int rel = tid >> 8;                  // 0 | 1
        int n   = (tid & 255) >> 1;          // local node 0..127
        int h   = (tid & 1) << 4;            // half-row offset in ints
        int nc  = m0 + n; if (nc >= N_NODES) nc = N_NODES - 1;
        const int* bsrc = (rel ? bkt2 : bkt1) + (size_t)nc * CAP + h;
        int* ldst = idsL + (rel * 128 + n) * IDS_STRIDE + h;
        uint4 b0 = *(const uint4*)(bsrc + 0);
        uint4 b1 = *(const uint4*)(bsrc + 4);
        uint4 b2 = *(const uint4*)(bsrc + 8);
        uint4 b3 = *(const uint4*)(bsrc + 12);
        *(uint4*)(ldst + 0)  = b0;
        *(uint4*)(ldst + 4)  = b1;
        *(uint4*)(ldst + 8)  = b2;
        *(uint4*)(ldst + 12) = b3;
    }

    // Per-thread gather counts (4 threads share a node).
    int c1 = cnt1[mA]; if (c1 > CAP) c1 = CAP;
    int c2 = cnt2[mA]; if (c2 > CAP) c2 = CAP;

    f32x4 acc[4][4] = {};
    uint4 ra;          // gather result for next tile (valid for kt>=8 stages)

    #define FOLD(v) { s0 += bfu_lo((v).x); s1 += bfu_hi((v).x); \
                      s2 += bfu_lo((v).y); s3 += bfu_hi((v).y); \
                      s4 += bfu_lo((v).z); s5 += bfu_hi((v).z); \
                      s6 += bfu_lo((v).w); s7 += bfu_hi((v).w); }

    for (int kt = 0; kt < 24; ++kt) {
        // ---- stage tile kt into LDS (async glds; gather via ds_write) ----
        if (kt < 8) {
            glds16(aSelfSrc + kt * 32, aDst);
        } else {
            *(uint4*)(Alds + wAoff) = ra;
        }
        glds16(bSrc0 + kt * 32, bDst0);
        glds16(bSrc1 + kt * 32, bDst1);

        // ---- pre-barrier: issue batch0 of next tile's gather ----
        const int ktn = kt + 1;
        uint4 gv[4];
        int cc = 0;
        const int* myids = idsL;
        const unsigned short* gbase = xb;
        if (ktn >= 8 && ktn < 24) {
            const bool r2g = (ktn >= 16);
            cc    = r2g ? c2 : c1;
            myids = idsL + ((r2g ? 128 : 0) + rowA) * IDS_STRIDE;
            gbase = xb + ((ktn - 8) & 7) * 32 + kqA * 8;
            #pragma unroll
            for (int e = 0; e < 4; ++e)
                if (e < cc) gv[e] = *(const uint4*)(gbase + (size_t)myids[e] * D);
        }
        __syncthreads();   // drains glds + ds_write + batch0 (vmcnt 0)

        // ---- post-barrier: fold batch0 (arrived), issue batch1 pre-MFMA --
        float s0 = 0.f, s1 = 0.f, s2 = 0.f, s3 = 0.f;
        float s4 = 0.f, s5 = 0.f, s6 = 0.f, s7 = 0.f;
        if (ktn >= 8 && ktn < 24) {
            #pragma unroll
            for (int e = 0; e < 4; ++e)
                if (e < cc) FOLD(gv[e]);
            #pragma unroll
            for (int e = 4; e < 8; ++e)          // batch1: in flight across MFMA
                if (e < cc) gv[e - 4] = *(const uint4*)(gbase + (size_t)myids[e] * D);
        }

        // ---- fragments + MFMA (tile kt) ----
        bf16x8 b0f = *(const bf16x8*)(Blds + (wn +  0 + l15) * 32 + ((quad ^ swz) * 8));
        bf16x8 b1f = *(const bf16x8*)(Blds + (wn + 16 + l15) * 32 + ((quad ^ swz) * 8));
        bf16x8 b2f = *(const bf16x8*)(Blds + (wn + 32 + l15) * 32 + ((quad ^ swz) * 8));
        bf16x8 b3f = *(const bf16x8*)(Blds + (wn + 48 + l15) * 32 + ((quad ^ swz) * 8));
        #pragma unroll
        for (int i = 0; i < 4; ++i) {
            bf16x8 afi = *(const bf16x8*)(Alds + (wm + i * 16 + l15) * 32 + ((quad ^ swz) * 8));
            acc[i][0] = __builtin_amdgcn_mfma_f32_16x16x32_bf16(afi, b0f, acc[i][0], 0, 0, 0);
            acc[i][1] = __builtin_amdgcn_mfma_f32_16x16x32_bf16(afi, b1f, acc[i][1], 0, 0, 0);
            acc[i][2] = __builtin_amdgcn_mfma_f32_16x16x32_bf16(afi, b2f, acc[i][2], 0, 0, 0);
            acc[i][3] = __builtin_amdgcn_mfma_f32_16x16x32_bf16(afi, b3f, acc[i][3], 0, 0, 0);
        }

        // ---- post-MFMA: fold batch1 + rare tail, pack bf16 -> ra ----
        if (ktn >= 8 && ktn < 24) {
            #pragma unroll
            for (int e = 4; e < 8; ++e)
                if (e < cc) FOLD(gv[e - 4]);
            for (int e0 = 8; e0 < cc; e0 += 4) {   // tail: P(deg>8)≈7%
                #pragma unroll
                for (int q = 0; q < 4; ++q)
                    if (e0 + q < cc) gv[q] = *(const uint4*)(gbase + (size_t)myids[e0 + q] * D);
                #pragma unroll
                for (int q = 0; q < 4; ++q)
                    if (e0 + q < cc) FOLD(gv[q]);
            }
            ra.x = (unsigned)f2bf(s0) | ((unsigned)f2bf(s1) << 16);
            ra.y = (unsigned)f2bf(s2) | ((unsigned)f2bf(s3) << 16);
            ra.z = (unsigned)f2bf(s4) | ((unsigned)f2bf(s5) << 16);
            ra.w = (unsigned)f2bf(s6) | ((unsigned)f2bf(s7) << 16);
        }
        __syncthreads();
    }
    #undef FOLD

    // Epilogue: D layout col=lane&15, row=quad*4+reg (m89/m91 verified).
    #pragma unroll
    for (int j = 0; j < 4; ++j) {
        int col = wn + j * 16 + l15;
        float bj = bias[col];
        #pragma unroll
        for (int i = 0; i < 4; ++i) {
            int rb = m0 + wm + i * 16 + quad * 4;
            #pragma unroll
            for (int r = 0; r < 4; ++r) {
                int m = rb + r;
                if (m < N_NODES)
                    __builtin_nontemporal_store(
                        fmaxf(acc[i][j][r] + bj, 0.f),
                        out + (size_t)m * D + col);
            }
        }
    }
}

extern "C" void kernel_launch(void* const* d_in, const int* in_sizes, int n_in,
                              void* d_out, int out_size, void* d_ws, size_t ws_size,
                              hipStream_t stream) {
    const float* x    = (const float*)d_in[0];
    const float* Ws   = (const float*)d_in[1];
    const float* W1   = (const float*)d_in[2];
    const float* W2   = (const float*)d_in[3];
    const float* bias = (const float*)d_in[4];
    const int* src1   = (const int*)d_in[5];
    const int* dst1   = (const int*)d_in[6];
    const int* src2   = (const int*)d_in[7];
    const int* dst2   = (const int*)d_in[8];
    float* out = (float*)d_out;

    // Workspace layout (total 78.4 MB):
    char* p = (char*)d_ws;
    unsigned short* xb  = (unsigned short*)p; p += (size_t)N_NODES * D * 2;  // 51.2 MB
    int* cnt1 = (int*)p; p += (size_t)N_NODES * 4;                           // 0.4 MB
    int* cnt2 = (int*)p; p += (size_t)N_NODES * 4;                           // 0.4 MB
    int* bkt1 = (int*)p; p += (size_t)N_NODES * CAP * 4;                     // 12.8 MB
    int* bkt2 = (int*)p; p += (size_t)N_NODES * CAP * 4;                     // 12.8 MB
    unsigned short* Wt = (unsigned short*)p;                                 // 0.39 MB

    (void)hipMemsetAsync(cnt1, 0, (size_t)2 * N_NODES * 4, stream);

    prep_kernel<<<PREP_BLOCKS, 256, 0, stream>>>(
        x, xb, Ws, W1, W2, Wt, src1, dst1, src2, dst2, cnt1, cnt2, bkt1, bkt2);

    // Fused gather + MFMA GEMM + bias + relu, full-N blocks
    gemm_kernel<<<(N_NODES + 127) / 128, 512, 0, stream>>>(
        xb, cnt1, cnt2, bkt1, bkt2, Wt, bias, out);
}

// Round 5
// 415.970 us; speedup vs baseline: 2.0526x; 1.0062x over previous
//
#include <hip/hip_runtime.h>

#define N_NODES 100000
#define N_EDGES 500000
#define D 256
#define CAP 32          // bucket capacity per (node, relation); λ=5 ⇒ P(deg>32)≈1e-15
#define IDS_STRIDE 36   // idsL node stride in ints: 144B, 16B-aligned
#define BM 64           // rows per block (round-5: halved for 128B gather visits)

typedef __bf16 bf16x8 __attribute__((ext_vector_type(8)));
typedef float  f32x4  __attribute__((ext_vector_type(4)));

// ---- bf16 helpers (manual, RNE) -------------------------------------------
__device__ __forceinline__ unsigned short f2bf(float f) {
    unsigned int u = __float_as_uint(f);
    u += 0x7fffu + ((u >> 16) & 1u);
    return (unsigned short)(u >> 16);
}
__device__ __forceinline__ float bfu_lo(unsigned u) { return __uint_as_float(u << 16); }
__device__ __forceinline__ float bfu_hi(unsigned u) { return __uint_as_float(u & 0xffff0000u); }

// ---- async global->LDS, 16B per lane (dest = uniform base + lane*16) ------
__device__ __forceinline__ void glds16(const unsigned short* g, unsigned short* l) {
    __builtin_amdgcn_global_load_lds(
        (const __attribute__((address_space(1))) unsigned int*)g,
        (__attribute__((address_space(3))) unsigned int*)l,
        16, 0, 0);
}

// ---------------------------------------------------------------------------
// Prep kernel, WAVE-granular role interleave (unchanged from round 4).
// W-role writes Wt PRE-SWIZZLED (k' = k ^ (((n>>1)&3)<<3)) so the GEMM can
// stage B with linear-dest global_load_lds (m173 pattern).
// ---------------------------------------------------------------------------
#define PREP_BLOCKS 17188   // ceil(22*3125 waves / 4 per block)

__global__ __launch_bounds__(256) void prep_kernel(
    const float* __restrict__ x, unsigned short* __restrict__ xb,
    const float* __restrict__ Ws, const float* __restrict__ W1,
    const float* __restrict__ W2, unsigned short* __restrict__ Wt,
    const int* __restrict__ src1, const int* __restrict__ dst1,
    const int* __restrict__ src2, const int* __restrict__ dst2,
    int* __restrict__ cnt1, int* __restrict__ cnt2,
    int* __restrict__ bkt1, int* __restrict__ bkt2)
{
    const int wid  = blockIdx.x * 4 + (threadIdx.x >> 6);  // global wave id
    const int lane = threadIdx.x & 63;
    const int group = wid / 22;
    const int pos   = wid - group * 22;

    if (pos < 16) {
        // ---- convert role: x fp32 -> xb bf16, 8 elems/lane, coalesced ----
        int cw = group * 16 + pos;
        if (cw >= 50000) return;
        size_t i = (size_t)cw * 512 + (size_t)lane * 8;
        float4 a = *(const float4*)(x + i);
        float4 c = *(const float4*)(x + i + 4);
        union { unsigned short s[8]; uint4 u; } o;
        o.s[0] = f2bf(a.x); o.s[1] = f2bf(a.y); o.s[2] = f2bf(a.z); o.s[3] = f2bf(a.w);
        o.s[4] = f2bf(c.x); o.s[5] = f2bf(c.y); o.s[6] = f2bf(c.z); o.s[7] = f2bf(c.w);
        *(uint4*)(xb + i) = o.u;
    } else if (pos < 21) {
        // ---- bucket role: 1 edge/lane, cnt/bkt atomics (L2-resident) ----
        int bw = group * 5 + (pos - 16);
        int e = bw * 64 + lane;
        if (e >= 2 * N_EDGES) return;
        bool r2 = (e >= N_EDGES);
        const int* src = r2 ? src2 : src1;
        const int* dst = r2 ? dst2 : dst1;
        int* cnt = r2 ? cnt2 : cnt1;
        int* bkt = r2 ? bkt2 : bkt1;
        int ei = r2 ? e - N_EDGES : e;
        int s = src[ei], d = dst[ei];
        int p = atomicAdd(&cnt[d], 1);
        if (p < CAP) bkt[d * CAP + p] = s;
    } else {
        // ---- W-prep role: Wt[n][k^swz] = bf16(scale_k * W[k%256][n]) ----
        int idx = group * 64 + lane;
        if (idx >= 3 * D * D) return;
        int k = idx >> 8;
        int n = idx & (D - 1);
        const float* W = (k < D) ? Ws : (k < 2 * D ? W1 : W2);
        float scale = (k < D) ? 1.1f : 1.0f;
        int dk = k ^ ((((n >> 1) & 3)) << 3);   // pre-swizzle 16B chunk slot
        Wt[(size_t)n * (3 * D) + dk] = f2bf(W[(size_t)(k & (D - 1)) * D + n] * scale);
    }
}

// ---------------------------------------------------------------------------
// Fused gather + MFMA GEMM, round-5: BURST SIZE + DOUBLE BUFFER.
//   out = relu( [xb | gather1(xb) | gather2(xb)] @ Wt^T + bias )
// Round-4 post-mortem: FETCH rose to 426MB — 64B random gather visits waste
// half of every >=128B fill and defeat L3 retention; and glds for tile kt was
// drained at the SAME iteration's barrier (exposed ~600cy/tile; MfmaUtil 7%).
// Fix:
//  * BM=64, 8 threads/node: gather tiles processed in PAIRS, each edge visit
//    reads 128B contiguous (per-thread 16B at pair_off + tg*16). Transactions
//    halve; fills fully used.
//  * Alds[2]/Blds[2] double buffer: glds(kt+1) issues at top of iteration kt
//    (full MFMA+fold window to land); ONE barrier per iteration.
//  * Pair pipeline over iterations (S-2 even, S-1 odd), pair S∈{8,10,..,22}:
//      even S-2 ph1: issue b0 (e0..3)  [lands across the barrier]
//      odd  S-1 ph1: issue b1 (e4..9, covers deg<=10); fold b0
//      odd  S-1 ph3: fold b1; rare tail e>=10; pack ra;
//                    tg<4 ds_write tile S into nxt
//      even S   ph1: tg>=4 ds_write tile S+1 into nxt
//  * acc[2][4] = 32 AGPRs; worst in-flight ~100 unified < 128 cap of (512,4)
//    -> 2 blocks/CU (LDS 58KB), co-resident block hides barrier drains.
// ---------------------------------------------------------------------------
__global__ __launch_bounds__(512, 4) void gemm_kernel(
    const unsigned short* __restrict__ xb,
    const int* __restrict__ cnt1, const int* __restrict__ cnt2,
    const int* __restrict__ bkt1, const int* __restrict__ bkt2,
    const unsigned short* __restrict__ Wt,   // [256 n][768 k] bf16, PRE-SWIZZLED
    const float* __restrict__ bias, float* __restrict__ out)
{
    __shared__ unsigned short Alds[2][BM * 32];     // 2 x 4 KB
    __shared__ unsigned short Blds[2][256 * 32];    // 2 x 16 KB
    __shared__ int idsL[2 * BM * IDS_STRIDE];       // 18.4 KB

    const int tid  = threadIdx.x;
    const int lane = tid & 63;
    const int wave = tid >> 6;          // 0..7
    const int quad = lane >> 4;
    const int l15  = lane & 15;
    const int m0 = blockIdx.x * BM;
    const int wm = (wave >> 2) * 32;    // 2 m-waves x 4 n-waves
    const int wn = (wave & 3) * 64;

    // Gather geometry: 8 threads per node; thread owns 16B of each 128B pair.
    const int rowA = tid >> 3;          // local node 0..63
    const int tg   = tid & 7;           // pair-chunk owner 0..7
    int mA = m0 + rowA; if (mA >= N_NODES) mA = N_NODES - 1;
    const int wAoff = rowA * 32 + (((tg & 3) ^ ((rowA >> 1) & 3)) * 8);
    const int swz = (l15 >> 1) & 3;     // read-side chunk swizzle

    // glds source geometry (wave slab of 16 rows; lane -> row,chunk)
    const int gr   = lane >> 2;
    const int gch  = lane & 3;
    const int gswz = (lane >> 3) & 3;   // (row>>1)&3 within slab
    int mSelf = m0 + (wave << 4) + gr;  // waves 0..3 stage A (16 rows each)
    if (mSelf >= N_NODES) mSelf = N_NODES - 1;
    const unsigned short* aSelfSrc = xb + (size_t)mSelf * D + ((gch ^ gswz) << 3);
    const unsigned short* bSrc0 = Wt + (size_t)((wave << 4) + gr) * (3 * D) + (gch << 3);
    const unsigned short* bSrc1 = bSrc0 + (size_t)128 * (3 * D);

    // ---- stage bucket ids into LDS: 8 ints per thread ----
    {
        int rel = tid >> 8;                  // 0 | 1
        int idx = tid & 255;
        int n   = idx >> 2;                  // local node 0..63
        int h   = (idx & 3) << 3;            // int offset 0/8/16/24
        int nc  = m0 + n; if (nc >= N_NODES) nc = N_NODES - 1;
        const int* bsrc = (rel ? bkt2 : bkt1) + (size_t)nc * CAP + h;
        int* ldst = idsL + (rel * BM + n) * IDS_STRIDE + h;
        uint4 q0 = *(const uint4*)(bsrc + 0);
        uint4 q1 = *(const uint4*)(bsrc + 4);
        *(uint4*)(ldst + 0) = q0;
        *(uint4*)(ldst + 4) = q1;
    }

    int c1 = cnt1[mA]; if (c1 > CAP) c1 = CAP;
    int c2 = cnt2[mA]; if (c2 > CAP) c2 = CAP;

    // Prologue: tile 0 into buffer 0.
    if (wave < 4) glds16(aSelfSrc, &Alds[0][wave * 512]);
    glds16(bSrc0, &Blds[0][wave * 512]);
    glds16(bSrc1, &Blds[0][4096 + wave * 512]);

    f32x4 acc[2][4] = {};
    uint4 gv0[4];                       // b0 batch, lives across even barrier
    uint4 ra;                           // packed pair result (8 bf16)
    int cc = 0;
    const int* myids = idsL;
    const unsigned short* gbase = xb;

    __syncthreads();

    #define FOLD(v) { s0 += bfu_lo((v).x); s1 += bfu_hi((v).x); \
                      s2 += bfu_lo((v).y); s3 += bfu_hi((v).y); \
                      s4 += bfu_lo((v).z); s5 += bfu_hi((v).z); \
                      s6 += bfu_lo((v).w); s7 += bfu_hi((v).w); }

    for (int kt = 0; kt < 24; ++kt) {
        const int cur = kt & 1, nxt = cur ^ 1;
        const int ktn = kt + 1;
        const bool odd = kt & 1;
        const bool oddWork = odd && kt >= 7 && kt <= 21;

        // ---------- phase 1: stage next tile; gather pipeline ----------
        if (ktn < 24) {
            if (ktn < 8) { if (wave < 4) glds16(aSelfSrc + ktn * 32, &Alds[nxt][wave * 512]); }
            glds16(bSrc0 + ktn * 32, &Blds[nxt][wave * 512]);
            glds16(bSrc1 + ktn * 32, &Blds[nxt][4096 + wave * 512]);
        }

        float s0 = 0.f, s1 = 0.f, s2 = 0.f, s3 = 0.f,
              s4 = 0.f, s5 = 0.f, s6 = 0.f, s7 = 0.f;
        uint4 gv1[6];

        if (!odd) {
            if (kt >= 8 && tg >= 4)                 // write tile kt+1 (odd half)
                *(uint4*)(&Alds[nxt][wAoff]) = ra;
            if (kt >= 6 && kt <= 20) {              // start pair S = kt+2
                const int S = kt + 2;
                const bool r2g = (S >= 16);
                cc    = r2g ? c2 : c1;
                myids = idsL + ((r2g ? BM : 0) + rowA) * IDS_STRIDE;
                gbase = xb + ((S - 8) & 7) * 32 + tg * 8;
                #pragma unroll
                for (int e = 0; e < 4; ++e)
                    if (e < cc) gv0[e] = *(const uint4*)(gbase + (size_t)myids[e] * D);
            }
        } else if (oddWork) {
            // issue b1 first (max window across MFMA), then fold b0 (landed)
            #pragma unroll
            for (int e = 4; e < 10; ++e)
                if (e < cc) gv1[e - 4] = *(const uint4*)(gbase + (size_t)myids[e] * D);
            #pragma unroll
            for (int e = 0; e < 4; ++e)
                if (e < cc) FOLD(gv0[e]);
        }

        // ---------- phase 2: MFMA on current buffer ----------
        {
            const unsigned short* Ab = Alds[cur];
            const unsigned short* Bb = Blds[cur];
            bf16x8 b0f = *(const bf16x8*)(Bb + (wn +  0 + l15) * 32 + ((quad ^ swz) * 8));
            bf16x8 b1f = *(const bf16x8*)(Bb + (wn + 16 + l15) * 32 + ((quad ^ swz) * 8));
            bf16x8 b2f = *(const bf16x8*)(Bb + (wn + 32 + l15) * 32 + ((quad ^ swz) * 8));
            bf16x8 b3f = *(const bf16x8*)(Bb + (wn + 48 + l15) * 32 + ((quad ^ swz) * 8));
            #pragma unroll
            for (int i = 0; i < 2; ++i) {
                bf16x8 afi = *(const bf16x8*)(Ab + (wm + i * 16 + l15) * 32 + ((quad ^ swz) * 8));
                acc[i][0] = __builtin_amdgcn_mfma_f32_16x16x32_bf16(afi, b0f, acc[i][0], 0, 0, 0);
                acc[i][1] = __builtin_amdgcn_mfma_f32_16x16x32_bf16(afi, b1f, acc[i][1], 0, 0, 0);
                acc[i][2] = __builtin_amdgcn_mfma_f32_16x16x32_bf16(afi, b2f, acc[i][2], 0, 0, 0);
                acc[i][3] = __builtin_amdgcn_mfma_f32_16x16x32_bf16(afi, b3f, acc[i][3], 0, 0, 0);
            }
        }

        // ---------- phase 3: fold b1 (+tail), pack, write even half ----------
        if (oddWork) {
            #pragma unroll
            for (int e = 4; e < 10; ++e)
                if (e < cc) FOLD(gv1[e - 4]);
            for (int e = 10; e < cc; ++e) {          // tail: P(deg>10)≈1.4%
                uint4 t = *(const uint4*)(gbase + (size_t)myids[e] * D);
                FOLD(t);
            }
            ra.x = (unsigned)f2bf(s0) | ((unsigned)f2bf(s1) << 16);
            ra.y = (unsigned)f2bf(s2) | ((unsigned)f2bf(s3) << 16);
            ra.z = (unsigned)f2bf(s4) | ((unsigned)f2bf(s5) << 16);
            ra.w = (unsigned)f2bf(s6) | ((unsigned)f2bf(s7) << 16);
            if (tg < 4)                              // write tile kt+1 (even half)
                *(uint4*)(&Alds[nxt][wAoff]) = ra;
        }
        __syncthreads();
    }
    #undef FOLD

    // Epilogue: D layout col=lane&15, row=quad*4+reg (m89/m91 verified).
    #pragma unroll
    for (int j = 0; j < 4; ++j) {
        int col = wn + j * 16 + l15;
        float bj = bias[col];
        #pragma unroll
        for (int i = 0; i < 2; ++i) {
            int rb = m0 + wm + i * 16 + quad * 4;
            #pragma unroll
            for (int r = 0; r < 4; ++r) {
                int m = rb + r;
                if (m < N_NODES)
                    __builtin_nontemporal_store(
                        fmaxf(acc[i][j][r] + bj, 0.f),
                        out + (size_t)m * D + col);
            }
        }
    }
}

extern "C" void kernel_launch(void* const* d_in, const int* in_sizes, int n_in,
                              void* d_out, int out_size, void* d_ws, size_t ws_size,
                              hipStream_t stream) {
    const float* x    = (const float*)d_in[0];
    const float* Ws   = (const float*)d_in[1];
    const float* W1   = (const float*)d_in[2];
    const float* W2   = (const float*)d_in[3];
    const float* bias = (const float*)d_in[4];
    const int* src1   = (const int*)d_in[5];
    const int* dst1   = (const int*)d_in[6];
    const int* src2   = (const int*)d_in[7];
    const int* dst2   = (const int*)d_in[8];
    float* out = (float*)d_out;

    // Workspace layout (total 78.4 MB):
    char* p = (char*)d_ws;
    unsigned short* xb  = (unsigned short*)p; p += (size_t)N_NODES * D * 2;  // 51.2 MB
    int* cnt1 = (int*)p; p += (size_t)N_NODES * 4;                           // 0.4 MB
    int* cnt2 = (int*)p; p += (size_t)N_NODES * 4;                           // 0.4 MB
    int* bkt1 = (int*)p; p += (size_t)N_NODES * CAP * 4;                     // 12.8 MB
    int* bkt2 = (int*)p; p += (size_t)N_NODES * CAP * 4;                     // 12.8 MB
    unsigned short* Wt = (unsigned short*)p;                                 // 0.39 MB

    (void)hipMemsetAsync(cnt1, 0, (size_t)2 * N_NODES * 4, stream);

    prep_kernel<<<PREP_BLOCKS, 256, 0, stream>>>(
        x, xb, Ws, W1, W2, Wt, src1, dst1, src2, dst2, cnt1, cnt2, bkt1, bkt2);

    // Fused gather + MFMA GEMM + bias + relu, full-N blocks of 64 rows
    gemm_kernel<<<(N_NODES + BM - 1) / BM, 512, 0, stream>>>(
        xb, cnt1, cnt2, bkt1, bkt2, Wt, bias, out);
}